// Round 6
// baseline (143.821 us; speedup 1.0000x reference)
//
#include <hip/hip_runtime.h>
#include <hip/hip_bf16.h>

// Problem: AdditiveMul  (N_Q=2048, N_K=2048, N_HEAD=8, D_HEAD=64)
// out[i,j,h] = softmax_h( relu( dot(q[i,h,:], attn[0,h,0:64]) + dot(k[j,h,:], attn[0,h,64:128]) ) )
// Output: (2048, 2048, 8) f32 = 134 MB -> store-bandwidth bound.
//
// R6: persistent-row softmax. One block per i-row, each thread makes 16
// independent float4 stores (grid-stride within the row) so the store pipe
// stays saturated (fill kernel proves 6.8 TB/s with this shape). 2048 blocks
// = 8/CU = 32 waves/CU (full occupancy). Lane-pair math from R5 kept:
// lanes 2m/2m+1 split the 8 heads of one j, denominator via shfl_xor(,1),
// exp2 builtin, rcp, no max-subtract (absmax 2e-3 << 1.4e-2 threshold).

#define N_Q   2048
#define N_K   2048
#define N_HEAD 8
#define D_HEAD 64

// ---------------------------------------------------------------------------
// Kernel 1: sq[i,h] = dot(q[i,h,:], attn[h,0:64]); sk[j,h] = dot(k[j,h,:], attn[h,64:128])
// 8 lanes per (row,head); float4 loads; shuffle-reduce.
// ---------------------------------------------------------------------------
__global__ __launch_bounds__(256) void proj_kernel(
    const float* __restrict__ q, const float* __restrict__ k,
    const float* __restrict__ attn,
    float* __restrict__ sq, float* __restrict__ sk)
{
    int tid = blockIdx.x * blockDim.x + threadIdx.x;
    int lane8 = tid & 7;
    int pair  = tid >> 3;                 // [0, 2*N_Q*N_HEAD)
    const int PAIRS = N_Q * N_HEAD;
    bool is_k = pair >= PAIRS;
    int p = is_k ? (pair - PAIRS) : pair; // p = row*8 + h
    int h = p & (N_HEAD - 1);

    const float* src = is_k ? k : q;
    const float* a   = attn + h * (2 * D_HEAD) + (is_k ? D_HEAD : 0);

    const float4* s4 = (const float4*)(src + (size_t)p * D_HEAD + lane8 * 8);
    const float4* a4 = (const float4*)(a + lane8 * 8);
    float4 x0 = s4[0], x1 = s4[1];
    float4 w0 = a4[0], w1 = a4[1];
    float sum = x0.x*w0.x + x0.y*w0.y + x0.z*w0.z + x0.w*w0.w
              + x1.x*w1.x + x1.y*w1.y + x1.z*w1.z + x1.w*w1.w;

    sum += __shfl_xor(sum, 1);
    sum += __shfl_xor(sum, 2);
    sum += __shfl_xor(sum, 4);

    if (lane8 == 0) {
        (is_k ? sk : sq)[p] = sum;
    }
}

// ---------------------------------------------------------------------------
// Kernel 2: one block per row i. 16 iterations of 256 threads cover the
// row's 2*N_K float4 slots. Lane pair (2m, 2m+1) = halves 0/1 of one j.
// Every wave store instruction writes 1 KB fully dense; 16 independent
// stores per thread keep the write pipe busy.
// ---------------------------------------------------------------------------
__global__ __launch_bounds__(256) void softmax_kernel(
    const float* __restrict__ sq, const float* __restrict__ sk,
    float* __restrict__ out)
{
    const int i    = blockIdx.x;
    const int half = threadIdx.x & 1;

    float4 qv = *(const float4*)(sq + i * N_HEAD + half * 4);
    float* orow = out + (size_t)i * N_K * N_HEAD;

    const float LOG2E = 1.4426950408889634f;
    const int ITERS = 2 * N_K / 256;   // 16

    #pragma unroll 4
    for (int it = 0; it < ITERS; ++it) {
        int t = it * 256 + threadIdx.x;          // float4 slot in this row
        float4 kv = *(const float4*)(sk + t * 4);

        float v0 = __builtin_amdgcn_exp2f(fmaxf(qv.x + kv.x, 0.0f) * LOG2E);
        float v1 = __builtin_amdgcn_exp2f(fmaxf(qv.y + kv.y, 0.0f) * LOG2E);
        float v2 = __builtin_amdgcn_exp2f(fmaxf(qv.z + kv.z, 0.0f) * LOG2E);
        float v3 = __builtin_amdgcn_exp2f(fmaxf(qv.w + kv.w, 0.0f) * LOG2E);

        float ps = (v0 + v1) + (v2 + v3);
        float s  = ps + __shfl_xor(ps, 1);       // partner has other 4 heads
        float r  = __builtin_amdgcn_rcpf(s);

        float4 o = make_float4(v0 * r, v1 * r, v2 * r, v3 * r);
        *(float4*)(orow + t * 4) = o;
    }
}

extern "C" void kernel_launch(void* const* d_in, const int* in_sizes, int n_in,
                              void* d_out, int out_size, void* d_ws, size_t ws_size,
                              hipStream_t stream) {
    const float* q    = (const float*)d_in[0];
    const float* k    = (const float*)d_in[1];
    const float* attn = (const float*)d_in[2];
    float* out = (float*)d_out;

    float* sq = (float*)d_ws;            // N_Q*N_HEAD floats
    float* sk = sq + N_Q * N_HEAD;       // N_K*N_HEAD floats

    int total_threads = 2 * N_Q * N_HEAD * 8;   // 262144
    proj_kernel<<<dim3(total_threads / 256), dim3(256), 0, stream>>>(q, k, attn, sq, sk);

    // one block per row
    softmax_kernel<<<dim3(N_Q), dim3(256), 0, stream>>>(sq, sk, out);
}